// Round 10
// baseline (567.199 us; speedup 1.0000x reference)
//
#include <hip/hip_runtime.h>

#define BATCH 4
#define NFEAT 64
#define DGRP 8
#define HH 96
#define WW 96
#define HWP (HH*WW)

typedef short short4a __attribute__((ext_vector_type(4)));
typedef short short8 __attribute__((ext_vector_type(8)));
typedef float f32x4 __attribute__((ext_vector_type(4)));
typedef float f32x16 __attribute__((ext_vector_type(16)));

__device__ inline short f2bf(float f) {
  union { float f; unsigned u; } v; v.f = f;
  unsigned r = v.u + 0x7fff + ((v.u >> 16) & 1);
  return (short)(r >> 16);
}
__device__ inline float bf2f(short s) {
  return __uint_as_float(((unsigned)(unsigned short)s) << 16);
}

// ---------------------------------------------------------------------------
// om-weight prep, 32x32 MFMA-A-fragment-shuffled (proven R6):
// dst[t][tile(8)][kk(36)][lane(64)][8]; k = kk*16 + half*8 + j = p*64+c.
// ---------------------------------------------------------------------------
__global__ __launch_bounds__(256) void prep_om(
    const float* __restrict__ s0, const float* __restrict__ s1,
    const float* __restrict__ s2, const float* __restrict__ s3,
    short* __restrict__ dst) {
  int gid = blockIdx.x * 256 + threadIdx.x;
  if (gid >= 4 * 147456) return;
  int t = gid / 147456, r = gid % 147456;
  int tile = r / 18432, r2 = r % 18432;
  int kk = r2 / 512, r3 = r2 % 512;
  int lane = r3 / 8, j = r3 % 8;
  int col = lane & 31, half = lane >> 5;
  int oc = tile * 32 + col;
  int k = kk * 16 + half * 8 + j;
  int p = k >> 6, c = k & 63;
  const float* s = (t == 0) ? s0 : (t == 1) ? s1 : (t == 2) ? s2 : s3;
  float v = (oc < 216) ? s[(size_t)oc * 576 + c * 9 + p] : 0.f;
  dst[gid] = f2bf(v);
}

// ---------------------------------------------------------------------------
// dcn-weight prep, same 32x32 A-shuffle: dst[t][tile(2)][kk(36)][lane][8].
// ---------------------------------------------------------------------------
__global__ __launch_bounds__(256) void prep_dcnw(
    const float* __restrict__ s0, const float* __restrict__ s1,
    const float* __restrict__ s2, const float* __restrict__ s3,
    short* __restrict__ dst) {
  int gid = blockIdx.x * 256 + threadIdx.x;
  if (gid >= 4 * 36864) return;
  int t = gid / 36864, r = gid % 36864;
  int tile = r / 18432, r2 = r % 18432;
  int kk = r2 / 512, r3 = r2 % 512;
  int lane = r3 / 8, j = r3 % 8;
  int col = lane & 31, half = lane >> 5;
  int oc = tile * 32 + col;
  int k = kk * 16 + half * 8 + j;
  int p = k >> 6, c = k & 63;
  const float* s = (t == 0) ? s0 : (t == 1) ? s1 : (t == 2) ? s2 : s3;
  dst[gid] = f2bf(s[(size_t)oc * 576 + c * 9 + p]);
}

// ---------------------------------------------------------------------------
// gconv weight prep (proven R7): 16x16x32 A frags, group-pair block-diagonal.
// ---------------------------------------------------------------------------
struct GwArgs {
  const float* src[12];
  int cat[12];
  int base[13];
};

__global__ __launch_bounds__(256) void prep_gw(GwArgs a, short* __restrict__ dst) {
  int gid = blockIdx.x * 256 + threadIdx.x;
  if (gid >= a.base[12]) return;
  int t = 0;
  while (gid >= a.base[t + 1]) ++t;
  int r = gid - a.base[t];
  const float* s = a.src[t];
  const int tsz = a.cat[t] ? 4608 : 2560;
  int tile = r / tsz, r2 = r % tsz;
  int kk = r2 / 512, r3 = r2 % 512;
  int lane = r3 >> 3, j = r3 & 7;
  int m = lane & 15, quad = lane >> 4;
  int oc = tile * 16 + m;
  int j32 = quad * 8 + j;
  float val = 0.f;
  if (a.cat[t]) {
    int gsel = j32 >> 4, ssel = (j32 >> 3) & 1, ch8 = j32 & 7;
    if (gsel == (m >> 3)) val = s[oc * 144 + (2 * ch8 + ssel) * 9 + kk];
  } else {
    int tapsel = j32 >> 4, gsel = (j32 >> 3) & 1, ch8 = j32 & 7;
    int p = 2 * kk + tapsel;
    if (p < 9 && gsel == (m >> 3)) val = s[oc * 72 + ch8 * 9 + p];
  }
  dst[gid] = f2bf(val);
}

// ---------------------------------------------------------------------------
// Channel-major fp32 -> pixel-major bf16; z picks (nbr->nbrT, ref->refT).
// ---------------------------------------------------------------------------
__global__ __launch_bounds__(256) void transpose_bf16(
    const float* __restrict__ in0, short* __restrict__ out0,
    const float* __restrict__ in1, short* __restrict__ out1) {
  const float* in = blockIdx.z ? in1 : in0;
  short* out = blockIdx.z ? out1 : out0;
  __shared__ float s[64][65];
  const int p0 = blockIdx.x * 64;
  const int b = blockIdx.y;
  const int tx = threadIdx.x, ty = threadIdx.y;
  for (int c = ty; c < 64; c += 4)
    s[c][tx] = in[((size_t)b * NFEAT + c) * HWP + p0 + tx];
  __syncthreads();
  for (int p = ty; p < 64; p += 4)
    out[((size_t)b * HWP + p0 + p) * NFEAT + tx] = f2bf(s[tx][p]);
}

// ---------------------------------------------------------------------------
// Grouped 3x3 conv v3: LDS-staged input tile, 16 px/block, 4 waves = 4 oc
// tiles. CAT: row = 9 taps x 128 cat-ch (vc8 = 2*c8 + src). NOCAT: 10 taps
// (tap 9 = zeros) x 64 ch. Pitch chosen: words % 32 == 2 -> 2-way banks.
// ---------------------------------------------------------------------------
template <bool CAT, bool LRELU>
__device__ __forceinline__ void gconv_body(
    const short* __restrict__ in0, const short* __restrict__ in1,
    const short* __restrict__ Wsh, const float* __restrict__ bias,
    short* __restrict__ out, int pixbase, int b) {
  constexpr int NKK = CAT ? 9 : 5;
  constexpr int NC8 = CAT ? 16 : 8;     // 8-chunks per tap row
  constexpr int NTAP = CAT ? 9 : 10;    // staged taps (incl zero tap NOCAT)
  constexpr int PITCH = CAT ? 1156 : 644;  // shorts; words%32==2
  __shared__ short Ls[16 * PITCH];

  const int lane = threadIdx.x, t = threadIdx.y;
  const int n = lane & 15, quad = lane >> 4;
  const int lid = t * 64 + lane;

  // ---- stage ----
  const size_t bofs = (size_t)b * HWP * 64;
  for (int i = lid; i < 16 * NTAP * NC8; i += 256) {
    int row = i / (NTAP * NC8), q = i % (NTAP * NC8);
    int p = q / NC8, vc8 = q % NC8;
    short4a lo = {0, 0, 0, 0}, hi = {0, 0, 0, 0};
    if (p < 9) {
      int pix = pixbase + row;
      int yp = pix / WW, xp = pix % WW;
      int sy = yp + p / 3 - 1, sx = xp + p % 3 - 1;
      if (((unsigned)sy < (unsigned)HH) && ((unsigned)sx < (unsigned)WW)) {
        const short* src;
        int c8;
        if (CAT) {
          src = (vc8 & 1) ? in1 : in0;
          c8 = vc8 >> 1;
        } else {
          src = in0;
          c8 = vc8;
        }
        const short* sp = src + bofs + (size_t)(sy * WW + sx) * 64 + c8 * 8;
        lo = *(const short4a*)sp;
        hi = *(const short4a*)(sp + 4);
      }
    }
    short* dst = Ls + row * PITCH + q * 8;
    *(short4a*)dst = lo;
    *(short4a*)(dst + 4) = hi;
  }
  __syncthreads();

  // ---- A frags (prep-shuffled, coalesced) ----
  short8 A[NKK];
#pragma unroll
  for (int kk = 0; kk < NKK; ++kk)
    A[kk] = *(const short8*)(Wsh + ((size_t)(t * NKK + kk) * 64 + lane) * 8);

  // ---- MFMA ----
  f32x4 acc = {};
#pragma unroll
  for (int kk = 0; kk < NKK; ++kk) {
    int colo;
    if (CAT) {
      colo = kk * 128 + (4 * t + quad) * 8;
    } else {
      int p = 2 * kk + (quad >> 1);
      colo = p * 64 + (2 * t + (quad & 1)) * 8;
    }
    const short* bp = Ls + n * PITCH + colo;
    short4a l = *(const short4a*)bp, h = *(const short4a*)(bp + 4);
    short8 B = {l[0], l[1], l[2], l[3], h[0], h[1], h[2], h[3]};
    acc = __builtin_amdgcn_mfma_f32_16x16x32_bf16(A[kk], B, acc, 0, 0, 0);
  }

  // ---- epilogue ----
  const int ocb = t * 16 + quad * 4;
  float v0 = acc[0] + bias[ocb], v1 = acc[1] + bias[ocb + 1];
  float v2 = acc[2] + bias[ocb + 2], v3 = acc[3] + bias[ocb + 3];
  if (LRELU) {
    v0 = (v0 >= 0.f) ? v0 : 0.1f * v0;
    v1 = (v1 >= 0.f) ? v1 : 0.1f * v1;
    v2 = (v2 >= 0.f) ? v2 : 0.1f * v2;
    v3 = (v3 >= 0.f) ? v3 : 0.1f * v3;
  }
  short4a pk = {f2bf(v0), f2bf(v1), f2bf(v2), f2bf(v3)};
  *(short4a*)(out + ((size_t)b * HWP + pixbase + n) * 64 + ocb) = pk;
}

template <bool CAT, bool LRELU>
__global__ __launch_bounds__(256) void gconv_mfma(
    const short* __restrict__ in0, const short* __restrict__ in1,
    const short* __restrict__ Wsh, const float* __restrict__ bias,
    short* __restrict__ out) {
  gconv_body<CAT, LRELU>(in0, in1, Wsh, bias, out, blockIdx.x * 16, blockIdx.y);
}

// Merged dispatch for the 3 independent oc1 convs (all CAT+LRELU).
struct Oc1Args {
  const short* W[3];
  const float* bias[3];
  short* out[3];
};

__global__ __launch_bounds__(256) void gconv_oc1x3(
    const short* __restrict__ in0, const short* __restrict__ in1, Oc1Args a) {
  const int job = blockIdx.z;
  gconv_body<true, true>(in0, in1, a.W[job], a.bias[job], a.out[job],
                         blockIdx.x * 16, blockIdx.y);
}

// ---------------------------------------------------------------------------
// Offset/mask conv v4: 32-px blocks (2x occupancy vs R8), single-phase LDS
// staging (pitch 580: words%32==2 -> 2-way free), 2 oc-tiles/wave.
// Grid (288, BATCH), block (64,4) -> 4608 waves.
// ---------------------------------------------------------------------------
#define OPITCH 580
template <int D>
__global__ __launch_bounds__(256) void omconv_mfma(
    const short* __restrict__ pixT,  // (b, hw, 64) bf16
    const short* __restrict__ Wsh,   // shuffled [tile(8)][kk(36)][lane][8]
    const float* __restrict__ bias,  // (216)
    short* __restrict__ out) {       // (b, 216, hw) bf16
  const int lane = threadIdx.x, w = threadIdx.y;
  const int lid = w * 64 + lane;
  const int col = lane & 31, half = lane >> 5;
  const int pixbase = blockIdx.x * 32;
  const int b = blockIdx.y;

  __shared__ short Bs[32 * OPITCH];  // 37,120 B

  const short* pixb = pixT + (size_t)b * HWP * 64;
  for (int i = lid; i < 32 * 72; i += 256) {
    int row = i / 72, q = i % 72;
    int p = q >> 3, c8 = q & 7;
    int pix = pixbase + row;
    int yp = pix / WW, xp = pix % WW;
    int sy = yp + (p / 3 - 1) * D, sx = xp + (p % 3 - 1) * D;
    short4a lo = {0, 0, 0, 0}, hi = {0, 0, 0, 0};
    if (((unsigned)sy < (unsigned)HH) && ((unsigned)sx < (unsigned)WW)) {
      const short* src = pixb + (size_t)(sy * WW + sx) * 64 + c8 * 8;
      lo = *(const short4a*)src;
      hi = *(const short4a*)(src + 4);
    }
    short* dst = Bs + row * OPITCH + q * 8;
    *(short4a*)dst = lo;
    *(short4a*)(dst + 4) = hi;
  }
  __syncthreads();

  const short* aP0 = Wsh + ((size_t)(w * 36) * 64 + lane) * 8;
  const short* aP1 = Wsh + ((size_t)((w + 4) * 36) * 64 + lane) * 8;

  f32x16 acc0 = {}, acc1 = {};
#pragma unroll 6
  for (int kk = 0; kk < 36; ++kk) {
    short8 A0 = *(const short8*)(aP0 + (size_t)kk * 512);
    short8 A1 = *(const short8*)(aP1 + (size_t)kk * 512);
    const short* bp = Bs + col * OPITCH + kk * 16 + half * 8;
    short4a l = *(const short4a*)bp, h = *(const short4a*)(bp + 4);
    short8 B = {l[0], l[1], l[2], l[3], h[0], h[1], h[2], h[3]};
    acc0 = __builtin_amdgcn_mfma_f32_32x32x16_bf16(A0, B, acc0, 0, 0, 0);
    acc1 = __builtin_amdgcn_mfma_f32_32x32x16_bf16(A1, B, acc1, 0, 0, 0);
  }

  const int pix = pixbase + col;
#pragma unroll
  for (int r = 0; r < 16; ++r) {
    const int rrow = (r & 3) + 8 * (r >> 2) + 4 * half;
    const int oc0 = w * 32 + rrow;         // < 128 always valid
    const int oc1 = (w + 4) * 32 + rrow;   // may be pad
    out[((size_t)b * 216 + oc0) * HWP + pix] = f2bf(acc0[r] + bias[oc0]);
    if (oc1 < 216)
      out[((size_t)b * 216 + oc1) * HWP + pix] = f2bf(acc1[r] + bias[oc1]);
  }
}

// ---------------------------------------------------------------------------
// Fused DCN (proven R8): sample -> LDS (B-frag order) -> K-split GEMM.
// ---------------------------------------------------------------------------
template <int D, bool LRELU, bool PMOUT>
__global__ __launch_bounds__(256) void dcn_fused(
    const short* __restrict__ xT,   // (b, hw, 64) bf16 pixel-major
    const short* __restrict__ om,   // (b, 216, hw) bf16
    const short* __restrict__ Wd,   // shuffled [tile(2)][kk(36)][lane][8]
    const float* __restrict__ bias, // (64)
    void* __restrict__ outv) {
  __shared__ short Ls[36 * 512];
  __shared__ float red[2][64][17];
  const int tx = threadIdx.x, ty = threadIdx.y;
  const int pb = blockIdx.x, b = blockIdx.y;

  {
    const int px = tx, dg = ty;
    const int pix = pb * 32 + px;
    const int yp = pix / WW, xp = pix % WW;
    const size_t bOM = (size_t)b * 216 * HWP;
    const short* xb = xT + (size_t)b * HWP * 64 + dg * 8;
    short* Sp = Ls + (size_t)((dg & 1) * 32 + px) * 8;

#pragma unroll
    for (int k = 0; k < 9; ++k) {
      float dy = bf2f(om[bOM + (size_t)(dg * 18 + 2 * k) * HWP + pix]);
      float dxv = bf2f(om[bOM + (size_t)(dg * 18 + 2 * k + 1) * HWP + pix]);
      float mr = bf2f(om[bOM + (size_t)(144 + dg * 9 + k) * HWP + pix]);
      float m = 1.f / (1.f + __expf(-mr));
      float py = (float)(yp + (k / 3 - 1) * D) + dy;
      float px_ = (float)(xp + (k % 3 - 1) * D) + dxv;
      float y0f = floorf(py), x0f = floorf(px_);
      float ly = py - y0f, lx = px_ - x0f;
      int y0 = (int)y0f, x0 = (int)x0f;
      int y1 = y0 + 1, x1 = x0 + 1;
      bool vy0 = (unsigned)y0 < (unsigned)HH, vy1 = (unsigned)y1 < (unsigned)HH;
      bool vx0 = (unsigned)x0 < (unsigned)WW, vx1 = (unsigned)x1 < (unsigned)WW;
      int cy0 = min(max(y0, 0), HH - 1), cy1 = min(max(y1, 0), HH - 1);
      int cx0 = min(max(x0, 0), WW - 1), cx1 = min(max(x1, 0), WW - 1);
      float w00 = (vy0 && vx0) ? (1.f - ly) * (1.f - lx) * m : 0.f;
      float w01 = (vy0 && vx1) ? (1.f - ly) * lx * m : 0.f;
      float w10 = (vy1 && vx0) ? ly * (1.f - lx) * m : 0.f;
      float w11 = (vy1 && vx1) ? ly * lx * m : 0.f;
      short8 s00 = *(const short8*)(xb + (size_t)(cy0 * WW + cx0) * 64);
      short8 s01 = *(const short8*)(xb + (size_t)(cy0 * WW + cx1) * 64);
      short8 s10 = *(const short8*)(xb + (size_t)(cy1 * WW + cx0) * 64);
      short8 s11 = *(const short8*)(xb + (size_t)(cy1 * WW + cx1) * 64);
      short8 pk;
#pragma unroll
      for (int cl = 0; cl < 8; ++cl) {
        float v = w00 * bf2f(s00[cl]) + w01 * bf2f(s01[cl]) +
                  w10 * bf2f(s10[cl]) + w11 * bf2f(s11[cl]);
        pk[cl] = f2bf(v);
      }
      const int kk = k * 4 + (dg >> 1);
      *(short8*)(Sp + (size_t)kk * 512) = pk;
    }
  }
  __syncthreads();

  const int lid = ty * 32 + tx;
  const int lane = lid & 63, w = lid >> 6;
  const int col = lane & 31, half = lane >> 5;
  const int octile = w & 1, kh = w >> 1;
  const int pix = pb * 32 + col;

  const short* aP = Wd + ((size_t)(octile * 36) * 64 + lane) * 8;
  const short* bP = Ls + (size_t)lane * 8;

  f32x16 acc = {};
#pragma unroll 6
  for (int kk = 0; kk < 18; ++kk) {
    const int kkg = kh * 18 + kk;
    short8 A = *(const short8*)(aP + (size_t)kkg * 512);
    short8 B = *(const short8*)(bP + (size_t)kkg * 512);
    acc = __builtin_amdgcn_mfma_f32_32x32x16_bf16(A, B, acc, 0, 0, 0);
  }

  if (kh == 1) {
#pragma unroll
    for (int r = 0; r < 16; ++r) red[octile][lane][r] = acc[r];
  }
  __syncthreads();
  if (kh == 0) {
    if (PMOUT) {
      short* out = (short*)outv;
#pragma unroll
      for (int rg = 0; rg < 4; ++rg) {
        short4a pk;
#pragma unroll
        for (int i = 0; i < 4; ++i) {
          const int r = rg * 4 + i;
          const int oc = octile * 32 + i + 8 * rg + 4 * half;
          float v = acc[r] + red[octile][lane][r] + bias[oc];
          if (LRELU) v = (v >= 0.f) ? v : 0.1f * v;
          pk[i] = f2bf(v);
        }
        *(short4a*)(out + ((size_t)b * HWP + pix) * 64 + octile * 32 + 8 * rg + 4 * half) = pk;
      }
    } else {
      float* out = (float*)outv;
#pragma unroll
      for (int r = 0; r < 16; ++r) {
        const int oc = octile * 32 + (r & 3) + 8 * (r >> 2) + 4 * half;
        float v = acc[r] + red[octile][lane][r] + bias[oc];
        if (LRELU) v = (v >= 0.f) ? v : 0.1f * v;
        out[((size_t)b * NFEAT + oc) * HWP + pix] = v;
      }
    }
  }
}

// ---------------------------------------------------------------------------
extern "C" void kernel_launch(void* const* d_in, const int* in_sizes, int n_in,
                              void* d_out, int out_size, void* d_ws, size_t ws_size,
                              hipStream_t stream) {
  const float* nbr = (const float*)d_in[0];
  const float* ref = (const float*)d_in[1];
  auto f = [&](int i) { return (const float*)d_in[i]; };

  short* s0 = (short*)d_ws;
  const size_t PM = (size_t)BATCH * HWP * 64;   // 2,359,296 shorts
  short* omB = s0;                              // 7,962,624 shorts
  short* refT = omB + 7962624;
  short* pmA = refT + PM;
  short* pmB = pmA + PM;
  short* pmC = pmB + PM;
  short* pmD = pmC + PM;
  short* pmE = pmD + PM;
  short* pmF = pmE + PM;
  short* pmG = pmF + PM;
  short* wbf = pmG + PM;                        // 589,824
  short* wdcn = wbf + 589824;                   // 147,456
  short* wgc = wdcn + 147456;                   // 188,416
  short* nbrT = (short*)d_out;                  // dead before final write

  // ---- weight prep ----
  prep_om<<<(4 * 147456 + 255) / 256, 256, 0, stream>>>(f(6), f(18), f(30), f(38), wbf);
  prep_dcnw<<<(4 * 36864 + 255) / 256, 256, 0, stream>>>(f(8), f(20), f(32), f(40), wdcn);

  static const int gSrc[12] = {2, 4, 10, 12, 14, 16, 22, 24, 26, 28, 34, 36};
  static const int gCat[12] = {1, 0, 1, 1, 0, 1, 1, 1, 0, 1, 1, 0};
  GwArgs ga;
  int gb = 0;
  const short* wg[12];
  for (int t = 0; t < 12; ++t) {
    ga.src[t] = f(gSrc[t]);
    ga.cat[t] = gCat[t];
    ga.base[t] = gb;
    wg[t] = wgc + gb;
    gb += gCat[t] ? 18432 : 10240;
  }
  ga.base[12] = gb;  // 188,416
  prep_gw<<<(gb + 255) / 256, 256, 0, stream>>>(ga, wgc);

  short* wbf_l3 = wbf;
  short* wbf_l2 = wbf + 147456;
  short* wbf_l1 = wbf + 2 * 147456;
  short* wbf_cas = wbf + 3 * 147456;
  short* wd_l3 = wdcn;
  short* wd_l2 = wdcn + 36864;
  short* wd_l1 = wdcn + 2 * 36864;
  short* wd_cas = wdcn + 3 * 36864;

  dim3 gcGrid(576, BATCH), gcBlk(64, 4);
  dim3 oc1Grid(576, BATCH, 3);
  dim3 omGrid(288, BATCH), omBlk(64, 4);
  dim3 dfGrid(288, BATCH), dfBlk(32, 8);
  dim3 trGrid(HWP / 64, BATCH, 2), trBlk(64, 4);

  transpose_bf16<<<trGrid, trBlk, 0, stream>>>(nbr, nbrT, ref, refT);

  // ---- merged oc1 convs (l3->pmA, l2->pmF, l1->pmG) ----
  Oc1Args oa;
  oa.W[0] = wg[0]; oa.bias[0] = f(3);  oa.out[0] = pmA;
  oa.W[1] = wg[2]; oa.bias[1] = f(11); oa.out[1] = pmF;
  oa.W[2] = wg[6]; oa.bias[2] = f(23); oa.out[2] = pmG;
  gconv_oc1x3<<<oc1Grid, gcBlk, 0, stream>>>(nbrT, refT, oa);

  // ---- level 3 (dilation 5) ----
  gconv_mfma<false, true><<<gcGrid, gcBlk, 0, stream>>>(pmA, nullptr, wg[1], f(5), pmB);
  omconv_mfma<5><<<omGrid, omBlk, 0, stream>>>(pmB, wbf_l3, f(7), omB);
  dcn_fused<5, true, true><<<dfGrid, dfBlk, 0, stream>>>(nbrT, omB, wd_l3, f(9), pmC);
  // pmB = to_l3, pmC = tf_l3

  // ---- level 2 (dilation 3) ----
  gconv_mfma<true, true><<<gcGrid, gcBlk, 0, stream>>>(pmF, pmB, wg[3], f(13), pmD);
  gconv_mfma<false, true><<<gcGrid, gcBlk, 0, stream>>>(pmD, nullptr, wg[4], f(15), pmE);
  omconv_mfma<3><<<omGrid, omBlk, 0, stream>>>(pmE, wbf_l2, f(19), omB);
  dcn_fused<3, false, true><<<dfGrid, dfBlk, 0, stream>>>(nbrT, omB, wd_l2, f(21), pmD);
  gconv_mfma<true, true><<<gcGrid, gcBlk, 0, stream>>>(pmD, pmC, wg[5], f(17), pmA);
  // pmE = to_l2, pmA = tf_l2

  // ---- level 1 (dilation 1) ----
  gconv_mfma<true, true><<<gcGrid, gcBlk, 0, stream>>>(pmG, pmE, wg[7], f(25), pmB);
  gconv_mfma<false, true><<<gcGrid, gcBlk, 0, stream>>>(pmB, nullptr, wg[8], f(27), pmC);
  omconv_mfma<1><<<omGrid, omBlk, 0, stream>>>(pmC, wbf_l1, f(31), omB);
  dcn_fused<1, false, true><<<dfGrid, dfBlk, 0, stream>>>(nbrT, omB, wd_l1, f(33), pmD);
  gconv_mfma<true, false><<<gcGrid, gcBlk, 0, stream>>>(pmD, pmA, wg[9], f(29), pmB);
  // pmB = feat (no lrelu); nbrT (in d_out) now dead

  // ---- cascade (dilation 1) ----
  gconv_mfma<true, true><<<gcGrid, gcBlk, 0, stream>>>(pmB, refT, wg[10], f(35), pmC);
  gconv_mfma<false, true><<<gcGrid, gcBlk, 0, stream>>>(pmC, nullptr, wg[11], f(37), pmD);
  omconv_mfma<1><<<omGrid, omBlk, 0, stream>>>(pmD, wbf_cas, f(39), omB);
  dcn_fused<1, true, false><<<dfGrid, dfBlk, 0, stream>>>(pmB, omB, wd_cas, f(41), (float*)d_out);
}

// Round 11
// 551.015 us; speedup vs baseline: 1.0294x; 1.0294x over previous
//
#include <hip/hip_runtime.h>

#define BATCH 4
#define NFEAT 64
#define DGRP 8
#define HH 96
#define WW 96
#define HWP (HH*WW)

typedef short short4a __attribute__((ext_vector_type(4)));
typedef short short8 __attribute__((ext_vector_type(8)));
typedef float f32x4 __attribute__((ext_vector_type(4)));
typedef float f32x16 __attribute__((ext_vector_type(16)));

__device__ inline short f2bf(float f) {
  union { float f; unsigned u; } v; v.f = f;
  unsigned r = v.u + 0x7fff + ((v.u >> 16) & 1);
  return (short)(r >> 16);
}
__device__ inline float bf2f(short s) {
  return __uint_as_float(((unsigned)(unsigned short)s) << 16);
}

// ---------------------------------------------------------------------------
// om-weight prep, 32x32 MFMA-A-fragment-shuffled (proven R6):
// dst[t][tile(8)][kk(36)][lane(64)][8]; k = kk*16 + half*8 + j = p*64+c.
// ---------------------------------------------------------------------------
__global__ __launch_bounds__(256) void prep_om(
    const float* __restrict__ s0, const float* __restrict__ s1,
    const float* __restrict__ s2, const float* __restrict__ s3,
    short* __restrict__ dst) {
  int gid = blockIdx.x * 256 + threadIdx.x;
  if (gid >= 4 * 147456) return;
  int t = gid / 147456, r = gid % 147456;
  int tile = r / 18432, r2 = r % 18432;
  int kk = r2 / 512, r3 = r2 % 512;
  int lane = r3 / 8, j = r3 % 8;
  int col = lane & 31, half = lane >> 5;
  int oc = tile * 32 + col;
  int k = kk * 16 + half * 8 + j;
  int p = k >> 6, c = k & 63;
  const float* s = (t == 0) ? s0 : (t == 1) ? s1 : (t == 2) ? s2 : s3;
  float v = (oc < 216) ? s[(size_t)oc * 576 + c * 9 + p] : 0.f;
  dst[gid] = f2bf(v);
}

// ---------------------------------------------------------------------------
// dcn-weight prep, same 32x32 A-shuffle: dst[t][tile(2)][kk(36)][lane][8].
// ---------------------------------------------------------------------------
__global__ __launch_bounds__(256) void prep_dcnw(
    const float* __restrict__ s0, const float* __restrict__ s1,
    const float* __restrict__ s2, const float* __restrict__ s3,
    short* __restrict__ dst) {
  int gid = blockIdx.x * 256 + threadIdx.x;
  if (gid >= 4 * 36864) return;
  int t = gid / 36864, r = gid % 36864;
  int tile = r / 18432, r2 = r % 18432;
  int kk = r2 / 512, r3 = r2 % 512;
  int lane = r3 / 8, j = r3 % 8;
  int col = lane & 31, half = lane >> 5;
  int oc = tile * 32 + col;
  int k = kk * 16 + half * 8 + j;
  int p = k >> 6, c = k & 63;
  const float* s = (t == 0) ? s0 : (t == 1) ? s1 : (t == 2) ? s2 : s3;
  dst[gid] = f2bf(s[(size_t)oc * 576 + c * 9 + p]);
}

// ---------------------------------------------------------------------------
// gconv weight prep (proven R7): 16x16x32 A frags, group-pair block-diagonal.
// ---------------------------------------------------------------------------
struct GwArgs {
  const float* src[12];
  int cat[12];
  int base[13];
};

__global__ __launch_bounds__(256) void prep_gw(GwArgs a, short* __restrict__ dst) {
  int gid = blockIdx.x * 256 + threadIdx.x;
  if (gid >= a.base[12]) return;
  int t = 0;
  while (gid >= a.base[t + 1]) ++t;
  int r = gid - a.base[t];
  const float* s = a.src[t];
  const int tsz = a.cat[t] ? 4608 : 2560;
  int tile = r / tsz, r2 = r % tsz;
  int kk = r2 / 512, r3 = r2 % 512;
  int lane = r3 >> 3, j = r3 & 7;
  int m = lane & 15, quad = lane >> 4;
  int oc = tile * 16 + m;
  int j32 = quad * 8 + j;
  float val = 0.f;
  if (a.cat[t]) {
    int gsel = j32 >> 4, ssel = (j32 >> 3) & 1, ch8 = j32 & 7;
    if (gsel == (m >> 3)) val = s[oc * 144 + (2 * ch8 + ssel) * 9 + kk];
  } else {
    int tapsel = j32 >> 4, gsel = (j32 >> 3) & 1, ch8 = j32 & 7;
    int p = 2 * kk + tapsel;
    if (p < 9 && gsel == (m >> 3)) val = s[oc * 72 + ch8 * 9 + p];
  }
  dst[gid] = f2bf(val);
}

// ---------------------------------------------------------------------------
// Channel-major fp32 -> pixel-major bf16; z picks (nbr->nbrT, ref->refT).
// ---------------------------------------------------------------------------
__global__ __launch_bounds__(256) void transpose_bf16(
    const float* __restrict__ in0, short* __restrict__ out0,
    const float* __restrict__ in1, short* __restrict__ out1) {
  const float* in = blockIdx.z ? in1 : in0;
  short* out = blockIdx.z ? out1 : out0;
  __shared__ float s[64][65];
  const int p0 = blockIdx.x * 64;
  const int b = blockIdx.y;
  const int tx = threadIdx.x, ty = threadIdx.y;
  for (int c = ty; c < 64; c += 4)
    s[c][tx] = in[((size_t)b * NFEAT + c) * HWP + p0 + tx];
  __syncthreads();
  for (int p = ty; p < 64; p += 4)
    out[((size_t)b * HWP + p0 + p) * NFEAT + tx] = f2bf(s[tx][p]);
}

// ---------------------------------------------------------------------------
// Grouped 3x3 conv on 16x16x32 MFMA — R7 direct-load version (proven best).
// Block (64,4): wave t = group-pair tile (16 oc), 32 pixels (2 N-tiles).
// ---------------------------------------------------------------------------
template <bool CAT, bool LRELU>
__device__ __forceinline__ void gconv_body(
    const short* __restrict__ in0, const short* __restrict__ in1,
    const short* __restrict__ Wsh, const float* __restrict__ bias,
    short* __restrict__ out, int pixbase, int b) {
  const int lane = threadIdx.x, t = threadIdx.y;
  const int n = lane & 15, quad = lane >> 4;
  constexpr int NKK = CAT ? 9 : 5;

  short8 A[NKK];
#pragma unroll
  for (int kk = 0; kk < NKK; ++kk)
    A[kk] = *(const short8*)(Wsh + ((size_t)(t * NKK + kk) * 64 + lane) * 8);

  const short* sb;
  if (CAT) {
    sb = ((quad & 1) ? in1 : in0) + (size_t)b * HWP * 64 + (2 * t + (quad >> 1)) * 8;
  } else {
    sb = in0 + (size_t)b * HWP * 64 + (2 * t + (quad & 1)) * 8;
  }

  f32x4 acc[2] = {};
#pragma unroll
  for (int nt = 0; nt < 2; ++nt) {
    const int pix = pixbase + nt * 16 + n;
    const int yp = pix / WW, xp = pix % WW;
#pragma unroll
    for (int kk = 0; kk < NKK; ++kk) {
      const int p = CAT ? kk : (2 * kk + (quad >> 1));
      short8 B = {0, 0, 0, 0, 0, 0, 0, 0};
      if (p < 9) {
        const int sy = yp + p / 3 - 1, sx = xp + p % 3 - 1;
        if (((unsigned)sy < (unsigned)HH) && ((unsigned)sx < (unsigned)WW))
          B = *(const short8*)(sb + (size_t)(sy * WW + sx) * 64);
      }
      acc[nt] = __builtin_amdgcn_mfma_f32_16x16x32_bf16(A[kk], B, acc[nt], 0, 0, 0);
    }
  }

  const int ocb = t * 16 + quad * 4;
  const float b0 = bias[ocb], b1 = bias[ocb + 1], b2 = bias[ocb + 2], b3 = bias[ocb + 3];
#pragma unroll
  for (int nt = 0; nt < 2; ++nt) {
    float v0 = acc[nt][0] + b0, v1 = acc[nt][1] + b1;
    float v2 = acc[nt][2] + b2, v3 = acc[nt][3] + b3;
    if (LRELU) {
      v0 = (v0 >= 0.f) ? v0 : 0.1f * v0;
      v1 = (v1 >= 0.f) ? v1 : 0.1f * v1;
      v2 = (v2 >= 0.f) ? v2 : 0.1f * v2;
      v3 = (v3 >= 0.f) ? v3 : 0.1f * v3;
    }
    short4a pk = {f2bf(v0), f2bf(v1), f2bf(v2), f2bf(v3)};
    *(short4a*)(out + ((size_t)b * HWP + pixbase + nt * 16 + n) * 64 + ocb) = pk;
  }
}

template <bool CAT, bool LRELU>
__global__ __launch_bounds__(256) void gconv_mfma(
    const short* __restrict__ in0, const short* __restrict__ in1,
    const short* __restrict__ Wsh, const float* __restrict__ bias,
    short* __restrict__ out) {
  gconv_body<CAT, LRELU>(in0, in1, Wsh, bias, out, blockIdx.x * 32, blockIdx.y);
}

// Merged dispatch for the 3 independent oc1 convs (all CAT+LRELU).
struct Oc1Args {
  const short* W[3];
  const float* bias[3];
  short* out[3];
};

__global__ __launch_bounds__(256) void gconv_oc1x3(
    const short* __restrict__ in0, const short* __restrict__ in1, Oc1Args a) {
  const int job = blockIdx.z;
  gconv_body<true, true>(in0, in1, a.W[job], a.bias[job], a.out[job],
                         blockIdx.x * 32, blockIdx.y);
}

// ---------------------------------------------------------------------------
// Offset/mask conv v4 (R9): 32-px blocks, single-phase LDS staging,
// 2 oc-tiles/wave. Grid (288, BATCH), block (64,4) -> 4608 waves.
// ---------------------------------------------------------------------------
#define OPITCH 580
template <int D>
__global__ __launch_bounds__(256) void omconv_mfma(
    const short* __restrict__ pixT,  // (b, hw, 64) bf16
    const short* __restrict__ Wsh,   // shuffled [tile(8)][kk(36)][lane][8]
    const float* __restrict__ bias,  // (216)
    short* __restrict__ out) {       // (b, 216, hw) bf16
  const int lane = threadIdx.x, w = threadIdx.y;
  const int lid = w * 64 + lane;
  const int col = lane & 31, half = lane >> 5;
  const int pixbase = blockIdx.x * 32;
  const int b = blockIdx.y;

  __shared__ short Bs[32 * OPITCH];  // 37,120 B

  const short* pixb = pixT + (size_t)b * HWP * 64;
  for (int i = lid; i < 32 * 72; i += 256) {
    int row = i / 72, q = i % 72;
    int p = q >> 3, c8 = q & 7;
    int pix = pixbase + row;
    int yp = pix / WW, xp = pix % WW;
    int sy = yp + (p / 3 - 1) * D, sx = xp + (p % 3 - 1) * D;
    short4a lo = {0, 0, 0, 0}, hi = {0, 0, 0, 0};
    if (((unsigned)sy < (unsigned)HH) && ((unsigned)sx < (unsigned)WW)) {
      const short* src = pixb + (size_t)(sy * WW + sx) * 64 + c8 * 8;
      lo = *(const short4a*)src;
      hi = *(const short4a*)(src + 4);
    }
    short* dst = Bs + row * OPITCH + q * 8;
    *(short4a*)dst = lo;
    *(short4a*)(dst + 4) = hi;
  }
  __syncthreads();

  const short* aP0 = Wsh + ((size_t)(w * 36) * 64 + lane) * 8;
  const short* aP1 = Wsh + ((size_t)((w + 4) * 36) * 64 + lane) * 8;

  f32x16 acc0 = {}, acc1 = {};
#pragma unroll 6
  for (int kk = 0; kk < 36; ++kk) {
    short8 A0 = *(const short8*)(aP0 + (size_t)kk * 512);
    short8 A1 = *(const short8*)(aP1 + (size_t)kk * 512);
    const short* bp = Bs + col * OPITCH + kk * 16 + half * 8;
    short4a l = *(const short4a*)bp, h = *(const short4a*)(bp + 4);
    short8 B = {l[0], l[1], l[2], l[3], h[0], h[1], h[2], h[3]};
    acc0 = __builtin_amdgcn_mfma_f32_32x32x16_bf16(A0, B, acc0, 0, 0, 0);
    acc1 = __builtin_amdgcn_mfma_f32_32x32x16_bf16(A1, B, acc1, 0, 0, 0);
  }

  const int pix = pixbase + col;
#pragma unroll
  for (int r = 0; r < 16; ++r) {
    const int rrow = (r & 3) + 8 * (r >> 2) + 4 * half;
    const int oc0 = w * 32 + rrow;         // < 128 always valid
    const int oc1 = (w + 4) * 32 + rrow;   // may be pad
    out[((size_t)b * 216 + oc0) * HWP + pix] = f2bf(acc0[r] + bias[oc0]);
    if (oc1 < 216)
      out[((size_t)b * 216 + oc1) * HWP + pix] = f2bf(acc1[r] + bias[oc1]);
  }
}

// ---------------------------------------------------------------------------
// Fused DCN (proven R8): sample -> LDS (B-frag order) -> K-split GEMM.
// ---------------------------------------------------------------------------
template <int D, bool LRELU, bool PMOUT>
__global__ __launch_bounds__(256) void dcn_fused(
    const short* __restrict__ xT,   // (b, hw, 64) bf16 pixel-major
    const short* __restrict__ om,   // (b, 216, hw) bf16
    const short* __restrict__ Wd,   // shuffled [tile(2)][kk(36)][lane][8]
    const float* __restrict__ bias, // (64)
    void* __restrict__ outv) {
  __shared__ short Ls[36 * 512];
  __shared__ float red[2][64][17];
  const int tx = threadIdx.x, ty = threadIdx.y;
  const int pb = blockIdx.x, b = blockIdx.y;

  {
    const int px = tx, dg = ty;
    const int pix = pb * 32 + px;
    const int yp = pix / WW, xp = pix % WW;
    const size_t bOM = (size_t)b * 216 * HWP;
    const short* xb = xT + (size_t)b * HWP * 64 + dg * 8;
    short* Sp = Ls + (size_t)((dg & 1) * 32 + px) * 8;

#pragma unroll
    for (int k = 0; k < 9; ++k) {
      float dy = bf2f(om[bOM + (size_t)(dg * 18 + 2 * k) * HWP + pix]);
      float dxv = bf2f(om[bOM + (size_t)(dg * 18 + 2 * k + 1) * HWP + pix]);
      float mr = bf2f(om[bOM + (size_t)(144 + dg * 9 + k) * HWP + pix]);
      float m = 1.f / (1.f + __expf(-mr));
      float py = (float)(yp + (k / 3 - 1) * D) + dy;
      float px_ = (float)(xp + (k % 3 - 1) * D) + dxv;
      float y0f = floorf(py), x0f = floorf(px_);
      float ly = py - y0f, lx = px_ - x0f;
      int y0 = (int)y0f, x0 = (int)x0f;
      int y1 = y0 + 1, x1 = x0 + 1;
      bool vy0 = (unsigned)y0 < (unsigned)HH, vy1 = (unsigned)y1 < (unsigned)HH;
      bool vx0 = (unsigned)x0 < (unsigned)WW, vx1 = (unsigned)x1 < (unsigned)WW;
      int cy0 = min(max(y0, 0), HH - 1), cy1 = min(max(y1, 0), HH - 1);
      int cx0 = min(max(x0, 0), WW - 1), cx1 = min(max(x1, 0), WW - 1);
      float w00 = (vy0 && vx0) ? (1.f - ly) * (1.f - lx) * m : 0.f;
      float w01 = (vy0 && vx1) ? (1.f - ly) * lx * m : 0.f;
      float w10 = (vy1 && vx0) ? ly * (1.f - lx) * m : 0.f;
      float w11 = (vy1 && vx1) ? ly * lx * m : 0.f;
      short8 s00 = *(const short8*)(xb + (size_t)(cy0 * WW + cx0) * 64);
      short8 s01 = *(const short8*)(xb + (size_t)(cy0 * WW + cx1) * 64);
      short8 s10 = *(const short8*)(xb + (size_t)(cy1 * WW + cx0) * 64);
      short8 s11 = *(const short8*)(xb + (size_t)(cy1 * WW + cx1) * 64);
      short8 pk;
#pragma unroll
      for (int cl = 0; cl < 8; ++cl) {
        float v = w00 * bf2f(s00[cl]) + w01 * bf2f(s01[cl]) +
                  w10 * bf2f(s10[cl]) + w11 * bf2f(s11[cl]);
        pk[cl] = f2bf(v);
      }
      const int kk = k * 4 + (dg >> 1);
      *(short8*)(Sp + (size_t)kk * 512) = pk;
    }
  }
  __syncthreads();

  const int lid = ty * 32 + tx;
  const int lane = lid & 63, w = lid >> 6;
  const int col = lane & 31, half = lane >> 5;
  const int octile = w & 1, kh = w >> 1;
  const int pix = pb * 32 + col;

  const short* aP = Wd + ((size_t)(octile * 36) * 64 + lane) * 8;
  const short* bP = Ls + (size_t)lane * 8;

  f32x16 acc = {};
#pragma unroll 6
  for (int kk = 0; kk < 18; ++kk) {
    const int kkg = kh * 18 + kk;
    short8 A = *(const short8*)(aP + (size_t)kkg * 512);
    short8 B = *(const short8*)(bP + (size_t)kkg * 512);
    acc = __builtin_amdgcn_mfma_f32_32x32x16_bf16(A, B, acc, 0, 0, 0);
  }

  if (kh == 1) {
#pragma unroll
    for (int r = 0; r < 16; ++r) red[octile][lane][r] = acc[r];
  }
  __syncthreads();
  if (kh == 0) {
    if (PMOUT) {
      short* out = (short*)outv;
#pragma unroll
      for (int rg = 0; rg < 4; ++rg) {
        short4a pk;
#pragma unroll
        for (int i = 0; i < 4; ++i) {
          const int r = rg * 4 + i;
          const int oc = octile * 32 + i + 8 * rg + 4 * half;
          float v = acc[r] + red[octile][lane][r] + bias[oc];
          if (LRELU) v = (v >= 0.f) ? v : 0.1f * v;
          pk[i] = f2bf(v);
        }
        *(short4a*)(out + ((size_t)b * HWP + pix) * 64 + octile * 32 + 8 * rg + 4 * half) = pk;
      }
    } else {
      float* out = (float*)outv;
#pragma unroll
      for (int r = 0; r < 16; ++r) {
        const int oc = octile * 32 + (r & 3) + 8 * (r >> 2) + 4 * half;
        float v = acc[r] + red[octile][lane][r] + bias[oc];
        if (LRELU) v = (v >= 0.f) ? v : 0.1f * v;
        out[((size_t)b * NFEAT + oc) * HWP + pix] = v;
      }
    }
  }
}

// ---------------------------------------------------------------------------
extern "C" void kernel_launch(void* const* d_in, const int* in_sizes, int n_in,
                              void* d_out, int out_size, void* d_ws, size_t ws_size,
                              hipStream_t stream) {
  const float* nbr = (const float*)d_in[0];
  const float* ref = (const float*)d_in[1];
  auto f = [&](int i) { return (const float*)d_in[i]; };

  short* s0 = (short*)d_ws;
  const size_t PM = (size_t)BATCH * HWP * 64;   // 2,359,296 shorts
  short* omB = s0;                              // 7,962,624 shorts
  short* refT = omB + 7962624;
  short* pmA = refT + PM;
  short* pmB = pmA + PM;
  short* pmC = pmB + PM;
  short* pmD = pmC + PM;
  short* pmE = pmD + PM;
  short* pmF = pmE + PM;
  short* pmG = pmF + PM;
  short* wbf = pmG + PM;                        // 589,824
  short* wdcn = wbf + 589824;                   // 147,456
  short* wgc = wdcn + 147456;                   // 188,416
  short* nbrT = (short*)d_out;                  // dead before final write

  // ---- weight prep ----
  prep_om<<<(4 * 147456 + 255) / 256, 256, 0, stream>>>(f(6), f(18), f(30), f(38), wbf);
  prep_dcnw<<<(4 * 36864 + 255) / 256, 256, 0, stream>>>(f(8), f(20), f(32), f(40), wdcn);

  static const int gSrc[12] = {2, 4, 10, 12, 14, 16, 22, 24, 26, 28, 34, 36};
  static const int gCat[12] = {1, 0, 1, 1, 0, 1, 1, 1, 0, 1, 1, 0};
  GwArgs ga;
  int gb = 0;
  const short* wg[12];
  for (int t = 0; t < 12; ++t) {
    ga.src[t] = f(gSrc[t]);
    ga.cat[t] = gCat[t];
    ga.base[t] = gb;
    wg[t] = wgc + gb;
    gb += gCat[t] ? 18432 : 10240;
  }
  ga.base[12] = gb;  // 188,416
  prep_gw<<<(gb + 255) / 256, 256, 0, stream>>>(ga, wgc);

  short* wbf_l3 = wbf;
  short* wbf_l2 = wbf + 147456;
  short* wbf_l1 = wbf + 2 * 147456;
  short* wbf_cas = wbf + 3 * 147456;
  short* wd_l3 = wdcn;
  short* wd_l2 = wdcn + 36864;
  short* wd_l1 = wdcn + 2 * 36864;
  short* wd_cas = wdcn + 3 * 36864;

  dim3 gcGrid(288, BATCH), gcBlk(64, 4);
  dim3 oc1Grid(288, BATCH, 3);
  dim3 omGrid(288, BATCH), omBlk(64, 4);
  dim3 dfGrid(288, BATCH), dfBlk(32, 8);
  dim3 trGrid(HWP / 64, BATCH, 2), trBlk(64, 4);

  transpose_bf16<<<trGrid, trBlk, 0, stream>>>(nbr, nbrT, ref, refT);

  // ---- merged oc1 convs (l3->pmA, l2->pmF, l1->pmG) ----
  Oc1Args oa;
  oa.W[0] = wg[0]; oa.bias[0] = f(3);  oa.out[0] = pmA;
  oa.W[1] = wg[2]; oa.bias[1] = f(11); oa.out[1] = pmF;
  oa.W[2] = wg[6]; oa.bias[2] = f(23); oa.out[2] = pmG;
  gconv_oc1x3<<<oc1Grid, gcBlk, 0, stream>>>(nbrT, refT, oa);

  // ---- level 3 (dilation 5) ----
  gconv_mfma<false, true><<<gcGrid, gcBlk, 0, stream>>>(pmA, nullptr, wg[1], f(5), pmB);
  omconv_mfma<5><<<omGrid, omBlk, 0, stream>>>(pmB, wbf_l3, f(7), omB);
  dcn_fused<5, true, true><<<dfGrid, dfBlk, 0, stream>>>(nbrT, omB, wd_l3, f(9), pmC);
  // pmB = to_l3, pmC = tf_l3

  // ---- level 2 (dilation 3) ----
  gconv_mfma<true, true><<<gcGrid, gcBlk, 0, stream>>>(pmF, pmB, wg[3], f(13), pmD);
  gconv_mfma<false, true><<<gcGrid, gcBlk, 0, stream>>>(pmD, nullptr, wg[4], f(15), pmE);
  omconv_mfma<3><<<omGrid, omBlk, 0, stream>>>(pmE, wbf_l2, f(19), omB);
  dcn_fused<3, false, true><<<dfGrid, dfBlk, 0, stream>>>(nbrT, omB, wd_l2, f(21), pmD);
  gconv_mfma<true, true><<<gcGrid, gcBlk, 0, stream>>>(pmD, pmC, wg[5], f(17), pmA);
  // pmE = to_l2, pmA = tf_l2

  // ---- level 1 (dilation 1) ----
  gconv_mfma<true, true><<<gcGrid, gcBlk, 0, stream>>>(pmG, pmE, wg[7], f(25), pmB);
  gconv_mfma<false, true><<<gcGrid, gcBlk, 0, stream>>>(pmB, nullptr, wg[8], f(27), pmC);
  omconv_mfma<1><<<omGrid, omBlk, 0, stream>>>(pmC, wbf_l1, f(31), omB);
  dcn_fused<1, false, true><<<dfGrid, dfBlk, 0, stream>>>(nbrT, omB, wd_l1, f(33), pmD);
  gconv_mfma<true, false><<<gcGrid, gcBlk, 0, stream>>>(pmD, pmA, wg[9], f(29), pmB);
  // pmB = feat (no lrelu); nbrT (in d_out) now dead

  // ---- cascade (dilation 1) ----
  gconv_mfma<true, true><<<gcGrid, gcBlk, 0, stream>>>(pmB, refT, wg[10], f(35), pmC);
  gconv_mfma<false, true><<<gcGrid, gcBlk, 0, stream>>>(pmC, nullptr, wg[11], f(37), pmD);
  omconv_mfma<1><<<omGrid, omBlk, 0, stream>>>(pmD, wbf_cas, f(39), omB);
  dcn_fused<1, true, false><<<dfGrid, dfBlk, 0, stream>>>(pmB, omB, wd_cas, f(41), (float*)d_out);
}

// Round 12
// 520.900 us; speedup vs baseline: 1.0889x; 1.0578x over previous
//
#include <hip/hip_runtime.h>

#define BATCH 4
#define NFEAT 64
#define DGRP 8
#define HH 96
#define WW 96
#define HWP (HH*WW)

typedef short short4a __attribute__((ext_vector_type(4)));
typedef short short8 __attribute__((ext_vector_type(8)));
typedef float f32x4 __attribute__((ext_vector_type(4)));
typedef float f32x16 __attribute__((ext_vector_type(16)));

__device__ inline short f2bf(float f) {
  union { float f; unsigned u; } v; v.f = f;
  unsigned r = v.u + 0x7fff + ((v.u >> 16) & 1);
  return (short)(r >> 16);
}
__device__ inline float bf2f(short s) {
  return __uint_as_float(((unsigned)(unsigned short)s) << 16);
}

// ---------------------------------------------------------------------------
// om-weight prep, 32x32 MFMA-A-fragment-shuffled (proven R6).
// ---------------------------------------------------------------------------
__global__ __launch_bounds__(256) void prep_om(
    const float* __restrict__ s0, const float* __restrict__ s1,
    const float* __restrict__ s2, const float* __restrict__ s3,
    short* __restrict__ dst) {
  int gid = blockIdx.x * 256 + threadIdx.x;
  if (gid >= 4 * 147456) return;
  int t = gid / 147456, r = gid % 147456;
  int tile = r / 18432, r2 = r % 18432;
  int kk = r2 / 512, r3 = r2 % 512;
  int lane = r3 / 8, j = r3 % 8;
  int col = lane & 31, half = lane >> 5;
  int oc = tile * 32 + col;
  int k = kk * 16 + half * 8 + j;
  int p = k >> 6, c = k & 63;
  const float* s = (t == 0) ? s0 : (t == 1) ? s1 : (t == 2) ? s2 : s3;
  float v = (oc < 216) ? s[(size_t)oc * 576 + c * 9 + p] : 0.f;
  dst[gid] = f2bf(v);
}

// ---------------------------------------------------------------------------
// dcn-weight prep, same 32x32 A-shuffle: dst[t][tile(2)][kk(36)][lane][8].
// ---------------------------------------------------------------------------
__global__ __launch_bounds__(256) void prep_dcnw(
    const float* __restrict__ s0, const float* __restrict__ s1,
    const float* __restrict__ s2, const float* __restrict__ s3,
    short* __restrict__ dst) {
  int gid = blockIdx.x * 256 + threadIdx.x;
  if (gid >= 4 * 36864) return;
  int t = gid / 36864, r = gid % 36864;
  int tile = r / 18432, r2 = r % 18432;
  int kk = r2 / 512, r3 = r2 % 512;
  int lane = r3 / 8, j = r3 % 8;
  int col = lane & 31, half = lane >> 5;
  int oc = tile * 32 + col;
  int k = kk * 16 + half * 8 + j;
  int p = k >> 6, c = k & 63;
  const float* s = (t == 0) ? s0 : (t == 1) ? s1 : (t == 2) ? s2 : s3;
  dst[gid] = f2bf(s[(size_t)oc * 576 + c * 9 + p]);
}

// ---------------------------------------------------------------------------
// gconv weight prep (proven R7): 16x16x32 A frags, group-pair block-diagonal.
// ---------------------------------------------------------------------------
struct GwArgs {
  const float* src[12];
  int cat[12];
  int base[13];
};

__global__ __launch_bounds__(256) void prep_gw(GwArgs a, short* __restrict__ dst) {
  int gid = blockIdx.x * 256 + threadIdx.x;
  if (gid >= a.base[12]) return;
  int t = 0;
  while (gid >= a.base[t + 1]) ++t;
  int r = gid - a.base[t];
  const float* s = a.src[t];
  const int tsz = a.cat[t] ? 4608 : 2560;
  int tile = r / tsz, r2 = r % tsz;
  int kk = r2 / 512, r3 = r2 % 512;
  int lane = r3 >> 3, j = r3 & 7;
  int m = lane & 15, quad = lane >> 4;
  int oc = tile * 16 + m;
  int j32 = quad * 8 + j;
  float val = 0.f;
  if (a.cat[t]) {
    int gsel = j32 >> 4, ssel = (j32 >> 3) & 1, ch8 = j32 & 7;
    if (gsel == (m >> 3)) val = s[oc * 144 + (2 * ch8 + ssel) * 9 + kk];
  } else {
    int tapsel = j32 >> 4, gsel = (j32 >> 3) & 1, ch8 = j32 & 7;
    int p = 2 * kk + tapsel;
    if (p < 9 && gsel == (m >> 3)) val = s[oc * 72 + ch8 * 9 + p];
  }
  dst[gid] = f2bf(val);
}

// ---------------------------------------------------------------------------
// Channel-major fp32 -> pixel-major bf16; z picks (nbr->nbrT, ref->refT).
// ---------------------------------------------------------------------------
__global__ __launch_bounds__(256) void transpose_bf16(
    const float* __restrict__ in0, short* __restrict__ out0,
    const float* __restrict__ in1, short* __restrict__ out1) {
  const float* in = blockIdx.z ? in1 : in0;
  short* out = blockIdx.z ? out1 : out0;
  __shared__ float s[64][65];
  const int p0 = blockIdx.x * 64;
  const int b = blockIdx.y;
  const int tx = threadIdx.x, ty = threadIdx.y;
  for (int c = ty; c < 64; c += 4)
    s[c][tx] = in[((size_t)b * NFEAT + c) * HWP + p0 + tx];
  __syncthreads();
  for (int p = ty; p < 64; p += 4)
    out[((size_t)b * HWP + p0 + p) * NFEAT + tx] = f2bf(s[tx][p]);
}

// ---------------------------------------------------------------------------
// Grouped 3x3 conv on 16x16x32 MFMA — R7 direct-load version (proven best).
// ---------------------------------------------------------------------------
template <bool CAT, bool LRELU>
__device__ __forceinline__ void gconv_body(
    const short* __restrict__ in0, const short* __restrict__ in1,
    const short* __restrict__ Wsh, const float* __restrict__ bias,
    short* __restrict__ out, int pixbase, int b) {
  const int lane = threadIdx.x, t = threadIdx.y;
  const int n = lane & 15, quad = lane >> 4;
  constexpr int NKK = CAT ? 9 : 5;

  short8 A[NKK];
#pragma unroll
  for (int kk = 0; kk < NKK; ++kk)
    A[kk] = *(const short8*)(Wsh + ((size_t)(t * NKK + kk) * 64 + lane) * 8);

  const short* sb;
  if (CAT) {
    sb = ((quad & 1) ? in1 : in0) + (size_t)b * HWP * 64 + (2 * t + (quad >> 1)) * 8;
  } else {
    sb = in0 + (size_t)b * HWP * 64 + (2 * t + (quad & 1)) * 8;
  }

  f32x4 acc[2] = {};
#pragma unroll
  for (int nt = 0; nt < 2; ++nt) {
    const int pix = pixbase + nt * 16 + n;
    const int yp = pix / WW, xp = pix % WW;
#pragma unroll
    for (int kk = 0; kk < NKK; ++kk) {
      const int p = CAT ? kk : (2 * kk + (quad >> 1));
      short8 B = {0, 0, 0, 0, 0, 0, 0, 0};
      if (p < 9) {
        const int sy = yp + p / 3 - 1, sx = xp + p % 3 - 1;
        if (((unsigned)sy < (unsigned)HH) && ((unsigned)sx < (unsigned)WW))
          B = *(const short8*)(sb + (size_t)(sy * WW + sx) * 64);
      }
      acc[nt] = __builtin_amdgcn_mfma_f32_16x16x32_bf16(A[kk], B, acc[nt], 0, 0, 0);
    }
  }

  const int ocb = t * 16 + quad * 4;
  const float b0 = bias[ocb], b1 = bias[ocb + 1], b2 = bias[ocb + 2], b3 = bias[ocb + 3];
#pragma unroll
  for (int nt = 0; nt < 2; ++nt) {
    float v0 = acc[nt][0] + b0, v1 = acc[nt][1] + b1;
    float v2 = acc[nt][2] + b2, v3 = acc[nt][3] + b3;
    if (LRELU) {
      v0 = (v0 >= 0.f) ? v0 : 0.1f * v0;
      v1 = (v1 >= 0.f) ? v1 : 0.1f * v1;
      v2 = (v2 >= 0.f) ? v2 : 0.1f * v2;
      v3 = (v3 >= 0.f) ? v3 : 0.1f * v3;
    }
    short4a pk = {f2bf(v0), f2bf(v1), f2bf(v2), f2bf(v3)};
    *(short4a*)(out + ((size_t)b * HWP + pixbase + nt * 16 + n) * 64 + ocb) = pk;
  }
}

template <bool CAT, bool LRELU>
__global__ __launch_bounds__(256) void gconv_mfma(
    const short* __restrict__ in0, const short* __restrict__ in1,
    const short* __restrict__ Wsh, const float* __restrict__ bias,
    short* __restrict__ out) {
  gconv_body<CAT, LRELU>(in0, in1, Wsh, bias, out, blockIdx.x * 32, blockIdx.y);
}

// Merged dispatch for the 3 independent oc1 convs (all CAT+LRELU).
struct Oc1Args {
  const short* W[3];
  const float* bias[3];
  short* out[3];
};

__global__ __launch_bounds__(256) void gconv_oc1x3(
    const short* __restrict__ in0, const short* __restrict__ in1, Oc1Args a) {
  const int job = blockIdx.z;
  gconv_body<true, true>(in0, in1, a.W[job], a.bias[job], a.out[job],
                         blockIdx.x * 32, blockIdx.y);
}

// ---------------------------------------------------------------------------
// Offset/mask conv v3 (proven R6/R8): 64-px blocks, two-phase LDS staging,
// 2x2 register blocking, bf16 out. Grid (144, BATCH), block (64,4).
// ---------------------------------------------------------------------------
#define BPITCH 324
template <int D>
__global__ __launch_bounds__(256) void omconv_mfma(
    const short* __restrict__ pixT,  // (b, hw, 64) bf16
    const short* __restrict__ Wsh,   // shuffled [tile(8)][kk(36)][lane][8]
    const float* __restrict__ bias,  // (216)
    short* __restrict__ out) {       // (b, 216, hw) bf16
  const int lane = threadIdx.x;
  const int w = threadIdx.y;
  const int lid = w * 64 + lane;
  const int col = lane & 31, half = lane >> 5;
  const int pixbase = blockIdx.x * 64;
  const int b = blockIdx.y;

  __shared__ short Bs[64 * BPITCH];

  const short* aP0 = Wsh + ((size_t)(w * 36) * 64) * 8 + (size_t)lane * 8;
  const short* aP1 = Wsh + ((size_t)((w + 4) * 36) * 64) * 8 + (size_t)lane * 8;
  const short* pixb = pixT + (size_t)b * HWP * 64;

  f32x16 acc00 = {}, acc01 = {}, acc10 = {}, acc11 = {};

  for (int ph = 0; ph < 2; ++ph) {
    const int ntap = ph ? 4 : 5, pbase = ph ? 5 : 0, kbase = ph ? 20 : 0;
    if (ph) __syncthreads();
    const int nchunk = 64 * ntap * 8;
    for (int i = lid; i < nchunk; i += 256) {
      int row = i / (ntap * 8), q = i % (ntap * 8);
      int p = pbase + (q >> 3), c8 = q & 7;
      int pix = pixbase + row;
      int yp = pix / WW, xp = pix % WW;
      int sy = yp + (p / 3 - 1) * D, sx = xp + (p % 3 - 1) * D;
      short4a lo = {0, 0, 0, 0}, hi = {0, 0, 0, 0};
      if (((unsigned)sy < (unsigned)HH) && ((unsigned)sx < (unsigned)WW)) {
        const short* src = pixb + (size_t)(sy * WW + sx) * 64 + c8 * 8;
        lo = *(const short4a*)src;
        hi = *(const short4a*)(src + 4);
      }
      short* dst = Bs + row * BPITCH + q * 8;
      *(short4a*)dst = lo;
      *(short4a*)(dst + 4) = hi;
    }
    __syncthreads();

    const int nkk = ntap * 4;
#pragma unroll 4
    for (int kk = 0; kk < nkk; ++kk) {
      const int kkg = kbase + kk;
      short8 A0 = *(const short8*)(aP0 + (size_t)kkg * 512);
      short8 A1 = *(const short8*)(aP1 + (size_t)kkg * 512);
      const short* b0 = Bs + col * BPITCH + kk * 16 + half * 8;
      const short* b1 = Bs + (32 + col) * BPITCH + kk * 16 + half * 8;
      short4a l0 = *(const short4a*)b0, h0 = *(const short4a*)(b0 + 4);
      short4a l1 = *(const short4a*)b1, h1 = *(const short4a*)(b1 + 4);
      short8 B0 = {l0[0], l0[1], l0[2], l0[3], h0[0], h0[1], h0[2], h0[3]};
      short8 B1 = {l1[0], l1[1], l1[2], l1[3], h1[0], h1[1], h1[2], h1[3]};
      acc00 = __builtin_amdgcn_mfma_f32_32x32x16_bf16(A0, B0, acc00, 0, 0, 0);
      acc01 = __builtin_amdgcn_mfma_f32_32x32x16_bf16(A0, B1, acc01, 0, 0, 0);
      acc10 = __builtin_amdgcn_mfma_f32_32x32x16_bf16(A1, B0, acc10, 0, 0, 0);
      acc11 = __builtin_amdgcn_mfma_f32_32x32x16_bf16(A1, B1, acc11, 0, 0, 0);
    }
  }

  const int pix0 = pixbase + col, pix1 = pixbase + 32 + col;
#pragma unroll
  for (int r = 0; r < 16; ++r) {
    const int rrow = (r & 3) + 8 * (r >> 2) + 4 * half;
    const int oc0 = w * 32 + rrow;
    const int oc1 = (w + 4) * 32 + rrow;
    const float bs0 = bias[oc0];
    out[((size_t)b * 216 + oc0) * HWP + pix0] = f2bf(acc00[r] + bs0);
    out[((size_t)b * 216 + oc0) * HWP + pix1] = f2bf(acc01[r] + bs0);
    if (oc1 < 216) {
      const float bs1 = bias[oc1];
      out[((size_t)b * 216 + oc1) * HWP + pix0] = f2bf(acc10[r] + bs1);
      out[((size_t)b * 216 + oc1) * HWP + pix1] = f2bf(acc11[r] + bs1);
    }
  }
}

// ---------------------------------------------------------------------------
// Fused DCN (proven R8): sample -> LDS (B-frag order) -> K-split GEMM.
// ---------------------------------------------------------------------------
template <int D, bool LRELU, bool PMOUT>
__global__ __launch_bounds__(256) void dcn_fused(
    const short* __restrict__ xT,   // (b, hw, 64) bf16 pixel-major
    const short* __restrict__ om,   // (b, 216, hw) bf16
    const short* __restrict__ Wd,   // shuffled [tile(2)][kk(36)][lane][8]
    const float* __restrict__ bias, // (64)
    void* __restrict__ outv) {
  __shared__ short Ls[36 * 512];
  __shared__ float red[2][64][17];
  const int tx = threadIdx.x, ty = threadIdx.y;
  const int pb = blockIdx.x, b = blockIdx.y;

  {
    const int px = tx, dg = ty;
    const int pix = pb * 32 + px;
    const int yp = pix / WW, xp = pix % WW;
    const size_t bOM = (size_t)b * 216 * HWP;
    const short* xb = xT + (size_t)b * HWP * 64 + dg * 8;
    short* Sp = Ls + (size_t)((dg & 1) * 32 + px) * 8;

#pragma unroll
    for (int k = 0; k < 9; ++k) {
      float dy = bf2f(om[bOM + (size_t)(dg * 18 + 2 * k) * HWP + pix]);
      float dxv = bf2f(om[bOM + (size_t)(dg * 18 + 2 * k + 1) * HWP + pix]);
      float mr = bf2f(om[bOM + (size_t)(144 + dg * 9 + k) * HWP + pix]);
      float m = 1.f / (1.f + __expf(-mr));
      float py = (float)(yp + (k / 3 - 1) * D) + dy;
      float px_ = (float)(xp + (k % 3 - 1) * D) + dxv;
      float y0f = floorf(py), x0f = floorf(px_);
      float ly = py - y0f, lx = px_ - x0f;
      int y0 = (int)y0f, x0 = (int)x0f;
      int y1 = y0 + 1, x1 = x0 + 1;
      bool vy0 = (unsigned)y0 < (unsigned)HH, vy1 = (unsigned)y1 < (unsigned)HH;
      bool vx0 = (unsigned)x0 < (unsigned)WW, vx1 = (unsigned)x1 < (unsigned)WW;
      int cy0 = min(max(y0, 0), HH - 1), cy1 = min(max(y1, 0), HH - 1);
      int cx0 = min(max(x0, 0), WW - 1), cx1 = min(max(x1, 0), WW - 1);
      float w00 = (vy0 && vx0) ? (1.f - ly) * (1.f - lx) * m : 0.f;
      float w01 = (vy0 && vx1) ? (1.f - ly) * lx * m : 0.f;
      float w10 = (vy1 && vx0) ? ly * (1.f - lx) * m : 0.f;
      float w11 = (vy1 && vx1) ? ly * lx * m : 0.f;
      short8 s00 = *(const short8*)(xb + (size_t)(cy0 * WW + cx0) * 64);
      short8 s01 = *(const short8*)(xb + (size_t)(cy0 * WW + cx1) * 64);
      short8 s10 = *(const short8*)(xb + (size_t)(cy1 * WW + cx0) * 64);
      short8 s11 = *(const short8*)(xb + (size_t)(cy1 * WW + cx1) * 64);
      short8 pk;
#pragma unroll
      for (int cl = 0; cl < 8; ++cl) {
        float v = w00 * bf2f(s00[cl]) + w01 * bf2f(s01[cl]) +
                  w10 * bf2f(s10[cl]) + w11 * bf2f(s11[cl]);
        pk[cl] = f2bf(v);
      }
      const int kk = k * 4 + (dg >> 1);
      *(short8*)(Sp + (size_t)kk * 512) = pk;
    }
  }
  __syncthreads();

  const int lid = ty * 32 + tx;
  const int lane = lid & 63, w = lid >> 6;
  const int col = lane & 31, half = lane >> 5;
  const int octile = w & 1, kh = w >> 1;
  const int pix = pb * 32 + col;

  const short* aP = Wd + ((size_t)(octile * 36) * 64 + lane) * 8;
  const short* bP = Ls + (size_t)lane * 8;

  f32x16 acc = {};
#pragma unroll 6
  for (int kk = 0; kk < 18; ++kk) {
    const int kkg = kh * 18 + kk;
    short8 A = *(const short8*)(aP + (size_t)kkg * 512);
    short8 B = *(const short8*)(bP + (size_t)kkg * 512);
    acc = __builtin_amdgcn_mfma_f32_32x32x16_bf16(A, B, acc, 0, 0, 0);
  }

  if (kh == 1) {
#pragma unroll
    for (int r = 0; r < 16; ++r) red[octile][lane][r] = acc[r];
  }
  __syncthreads();
  if (kh == 0) {
    if (PMOUT) {
      short* out = (short*)outv;
#pragma unroll
      for (int rg = 0; rg < 4; ++rg) {
        short4a pk;
#pragma unroll
        for (int i = 0; i < 4; ++i) {
          const int r = rg * 4 + i;
          const int oc = octile * 32 + i + 8 * rg + 4 * half;
          float v = acc[r] + red[octile][lane][r] + bias[oc];
          if (LRELU) v = (v >= 0.f) ? v : 0.1f * v;
          pk[i] = f2bf(v);
        }
        *(short4a*)(out + ((size_t)b * HWP + pix) * 64 + octile * 32 + 8 * rg + 4 * half) = pk;
      }
    } else {
      float* out = (float*)outv;
#pragma unroll
      for (int r = 0; r < 16; ++r) {
        const int oc = octile * 32 + (r & 3) + 8 * (r >> 2) + 4 * half;
        float v = acc[r] + red[octile][lane][r] + bias[oc];
        if (LRELU) v = (v >= 0.f) ? v : 0.1f * v;
        out[((size_t)b * NFEAT + oc) * HWP + pix] = v;
      }
    }
  }
}

// ---------------------------------------------------------------------------
extern "C" void kernel_launch(void* const* d_in, const int* in_sizes, int n_in,
                              void* d_out, int out_size, void* d_ws, size_t ws_size,
                              hipStream_t stream) {
  const float* nbr = (const float*)d_in[0];
  const float* ref = (const float*)d_in[1];
  auto f = [&](int i) { return (const float*)d_in[i]; };

  short* s0 = (short*)d_ws;
  const size_t PM = (size_t)BATCH * HWP * 64;   // 2,359,296 shorts
  short* omB = s0;                              // 7,962,624 shorts
  short* refT = omB + 7962624;
  short* pmA = refT + PM;
  short* pmB = pmA + PM;
  short* pmC = pmB + PM;
  short* pmD = pmC + PM;
  short* pmE = pmD + PM;
  short* pmF = pmE + PM;
  short* pmG = pmF + PM;
  short* wbf = pmG + PM;                        // 589,824
  short* wdcn = wbf + 589824;                   // 147,456
  short* wgc = wdcn + 147456;                   // 188,416
  short* nbrT = (short*)d_out;                  // dead before final write

  // ---- weight prep ----
  prep_om<<<(4 * 147456 + 255) / 256, 256, 0, stream>>>(f(6), f(18), f(30), f(38), wbf);
  prep_dcnw<<<(4 * 36864 + 255) / 256, 256, 0, stream>>>(f(8), f(20), f(32), f(40), wdcn);

  static const int gSrc[12] = {2, 4, 10, 12, 14, 16, 22, 24, 26, 28, 34, 36};
  static const int gCat[12] = {1, 0, 1, 1, 0, 1, 1, 1, 0, 1, 1, 0};
  GwArgs ga;
  int gb = 0;
  const short* wg[12];
  for (int t = 0; t < 12; ++t) {
    ga.src[t] = f(gSrc[t]);
    ga.cat[t] = gCat[t];
    ga.base[t] = gb;
    wg[t] = wgc + gb;
    gb += gCat[t] ? 18432 : 10240;
  }
  ga.base[12] = gb;  // 188,416
  prep_gw<<<(gb + 255) / 256, 256, 0, stream>>>(ga, wgc);

  short* wbf_l3 = wbf;
  short* wbf_l2 = wbf + 147456;
  short* wbf_l1 = wbf + 2 * 147456;
  short* wbf_cas = wbf + 3 * 147456;
  short* wd_l3 = wdcn;
  short* wd_l2 = wdcn + 36864;
  short* wd_l1 = wdcn + 2 * 36864;
  short* wd_cas = wdcn + 3 * 36864;

  dim3 gcGrid(288, BATCH), gcBlk(64, 4);
  dim3 oc1Grid(288, BATCH, 3);
  dim3 omGrid(144, BATCH), omBlk(64, 4);
  dim3 dfGrid(288, BATCH), dfBlk(32, 8);
  dim3 trGrid(HWP / 64, BATCH, 2), trBlk(64, 4);

  transpose_bf16<<<trGrid, trBlk, 0, stream>>>(nbr, nbrT, ref, refT);

  // ---- merged oc1 convs (l3->pmA, l2->pmF, l1->pmG) ----
  Oc1Args oa;
  oa.W[0] = wg[0]; oa.bias[0] = f(3);  oa.out[0] = pmA;
  oa.W[1] = wg[2]; oa.bias[1] = f(11); oa.out[1] = pmF;
  oa.W[2] = wg[6]; oa.bias[2] = f(23); oa.out[2] = pmG;
  gconv_oc1x3<<<oc1Grid, gcBlk, 0, stream>>>(nbrT, refT, oa);

  // ---- level 3 (dilation 5) ----
  gconv_mfma<false, true><<<gcGrid, gcBlk, 0, stream>>>(pmA, nullptr, wg[1], f(5), pmB);
  omconv_mfma<5><<<omGrid, omBlk, 0, stream>>>(pmB, wbf_l3, f(7), omB);
  dcn_fused<5, true, true><<<dfGrid, dfBlk, 0, stream>>>(nbrT, omB, wd_l3, f(9), pmC);
  // pmB = to_l3, pmC = tf_l3

  // ---- level 2 (dilation 3) ----
  gconv_mfma<true, true><<<gcGrid, gcBlk, 0, stream>>>(pmF, pmB, wg[3], f(13), pmD);
  gconv_mfma<false, true><<<gcGrid, gcBlk, 0, stream>>>(pmD, nullptr, wg[4], f(15), pmE);
  omconv_mfma<3><<<omGrid, omBlk, 0, stream>>>(pmE, wbf_l2, f(19), omB);
  dcn_fused<3, false, true><<<dfGrid, dfBlk, 0, stream>>>(nbrT, omB, wd_l2, f(21), pmD);
  gconv_mfma<true, true><<<gcGrid, gcBlk, 0, stream>>>(pmD, pmC, wg[5], f(17), pmA);
  // pmE = to_l2, pmA = tf_l2

  // ---- level 1 (dilation 1) ----
  gconv_mfma<true, true><<<gcGrid, gcBlk, 0, stream>>>(pmG, pmE, wg[7], f(25), pmB);
  gconv_mfma<false, true><<<gcGrid, gcBlk, 0, stream>>>(pmB, nullptr, wg[8], f(27), pmC);
  omconv_mfma<1><<<omGrid, omBlk, 0, stream>>>(pmC, wbf_l1, f(31), omB);
  dcn_fused<1, false, true><<<dfGrid, dfBlk, 0, stream>>>(nbrT, omB, wd_l1, f(33), pmD);
  gconv_mfma<true, false><<<gcGrid, gcBlk, 0, stream>>>(pmD, pmA, wg[9], f(29), pmB);
  // pmB = feat (no lrelu); nbrT (in d_out) now dead

  // ---- cascade (dilation 1) ----
  gconv_mfma<true, true><<<gcGrid, gcBlk, 0, stream>>>(pmB, refT, wg[10], f(35), pmC);
  gconv_mfma<false, true><<<gcGrid, gcBlk, 0, stream>>>(pmC, nullptr, wg[11], f(37), pmD);
  omconv_mfma<1><<<omGrid, omBlk, 0, stream>>>(pmD, wbf_cas, f(39), omB);
  dcn_fused<1, true, false><<<dfGrid, dfBlk, 0, stream>>>(pmB, omB, wd_cas, f(41), (float*)d_out);
}